// Round 10
// baseline (679.432 us; speedup 1.0000x reference)
//
#include <hip/hip_runtime.h>
#include <cstddef>
#include <cmath>

typedef __attribute__((ext_vector_type(8))) short bf16x8;
typedef __attribute__((ext_vector_type(4))) float f32x4;

static __device__ __forceinline__ f32x4 mfma16(bf16x8 a, bf16x8 b, f32x4 c) {
    return __builtin_amdgcn_mfma_f32_16x16x32_bf16(a, b, c, 0, 0, 0);
}
static __device__ __forceinline__ unsigned short f2bf(float f) {
    unsigned int u = __float_as_uint(f);
    return (unsigned short)((u + 0x7FFFu + ((u >> 16) & 1u)) >> 16);
}

// ============================ CSR build ============================
__global__ void k_init_cnt(unsigned int* __restrict__ cnt, int N) {
    int i = blockIdx.x * 256 + threadIdx.x;
    if (i < N) cnt[i] = 1u;   // self-loop pre-counted
}

__global__ void k_count(const int* __restrict__ ei, int E, unsigned int* __restrict__ cnt) {
    int e = blockIdx.x * 256 + threadIdx.x;
    if (e < E) atomicAdd(&cnt[ei[E + e]], 1u);
}

__global__ __launch_bounds__(1024) void k_scan(const unsigned int* __restrict__ cnt,
                                               unsigned int* __restrict__ off, int N) {
    __shared__ unsigned int sums[1024];
    int t = threadIdx.x;
    int chunk = (N + 1023) >> 10;
    int lo = t * chunk, hi = min(lo + chunk, N);
    unsigned int s = 0;
    for (int i = lo; i < hi; ++i) s += cnt[i];
    sums[t] = s;
    __syncthreads();
    for (int d = 1; d < 1024; d <<= 1) {
        unsigned int v = (t >= d) ? sums[t - d] : 0u;
        __syncthreads();
        sums[t] += v;
        __syncthreads();
    }
    unsigned int run = (t == 0) ? 0u : sums[t - 1];
    for (int i = lo; i < hi; ++i) { off[i] = run; run += cnt[i]; }
}

__global__ void k_fill(const unsigned int* __restrict__ off, unsigned int* __restrict__ cur,
                       unsigned int* __restrict__ list, int N) {
    int n = blockIdx.x * 256 + threadIdx.x;
    if (n < N) { unsigned int o = off[n]; list[o] = (unsigned int)n; cur[n] = o + 1u; }
}

__global__ void k_scatter(const int* __restrict__ ei, int E,
                          unsigned int* __restrict__ cur, unsigned int* __restrict__ list) {
    int e = blockIdx.x * 256 + threadIdx.x;
    if (e < E) {
        int d = ei[E + e];
        unsigned int p = atomicAdd(&cur[d], 1u);
        list[p] = (unsigned int)ei[e];
    }
}

// ====== weight converter: f32 [K][N] -> bf16 transposed [N][K] (W1 K-padded to 32) ======
__global__ void k_convert(const float* __restrict__ W1, const float* __restrict__ W2,
                          const float* __restrict__ W3, const float* __restrict__ W4,
                          const float* __restrict__ W5,
                          unsigned short* __restrict__ W1bt, unsigned short* __restrict__ W2bt,
                          unsigned short* __restrict__ W3bt, unsigned short* __restrict__ W4bt,
                          unsigned short* __restrict__ W5bt) {
    int id = blockIdx.x * 256 + threadIdx.x;
    if (id < 2048) {                               // W1: [6][64] -> [64][32] zero-padded
        int n = id >> 5, k = id & 31;
        W1bt[id] = (k < 6) ? f2bf(W1[k * 64 + n]) : (unsigned short)0;
    } else if (id < 2048 + 4096) {                 // W2: [64][64] -> [64][64]
        int t = id - 2048;
        int n = t >> 6, k = t & 63;
        W2bt[t] = f2bf(W2[k * 64 + n]);
    } else if (id < 6144 + 8192) {                 // W3: [64][128] -> [128][64]
        int t = id - 6144;
        int n = t >> 6, k = t & 63;
        W3bt[t] = f2bf(W3[k * 128 + n]);
    } else if (id < 14336 + 131072) {              // W4: [128][1024] -> [1024][128]
        int t = id - 14336;
        int n = t >> 7, k = t & 127;
        W4bt[t] = f2bf(W4[k * 1024 + n]);
    } else if (id < 145408 + 65536) {              // W5: [1024][64] -> [64][1024]
        int t = id - 145408;
        int n = t >> 10, k = t & 1023;
        W5bt[t] = f2bf(W5[k * 64 + n]);
    }
}

// ===================== fused edge+node kernel: 64 dsts/block, 4 waves =====================
// Wave wm owns dst/node rows [wm*16, wm*16+16) in BOTH phases -> Ag LDS rows are
// wave-private; edge->node handoff needs no barrier. G3f overlays Ag byte-exactly
// (same 68-f32 row stride) so the overlay is also wave-private. 2 barriers total.
// MFMA layouts (m89/m120-verified): A[m=lane&15][k=quad*8+j], B[k=quad*8+j][n=lane&15],
// C/D reg r = D[row=quad*4+r][col=lane&15].
#define NNODE 64
__global__ __launch_bounds__(256, 3) void fused_kernel(
    const float* __restrict__ x, const float* __restrict__ pos,
    const unsigned int* __restrict__ off, const unsigned int* __restrict__ cur,
    const unsigned int* __restrict__ list,
    const unsigned short* __restrict__ W1bt, const float* __restrict__ b1,
    const unsigned short* __restrict__ W2bt, const float* __restrict__ b2,
    const unsigned short* __restrict__ W3bt, const float* __restrict__ b3,
    const unsigned short* __restrict__ W4bt, const float* __restrict__ b4,
    const unsigned short* __restrict__ W5bt, const float* __restrict__ b5,
    const float* __restrict__ Wf, const float* __restrict__ bf,
    float* __restrict__ out, int N)
{
    // layout (52 KB -> 3 blocks/CU):
    //   [0      , 17408) Ag  f32 [64][68]   -> G3f f32 [64][68] (byte-exact overlay)
    //   [17408  , 26624) Hs  short [4][16*72]  -> head of os
    //   [26624  , 44032) G1s short [64][136]   -> tail of os overlays rows 0..4 (dead)
    //   [44032  , 53248) G2s short [64][72]
    __shared__ __align__(16) char smem[53248];
    float* Ag  = (float*)smem;
    short* Hs  = (short*)(smem + 17408);
    short* G1s = (short*)(smem + 26624);
    short* G2s = (short*)(smem + 44032);
    float* G3f = (float*)smem;
    float* os  = (float*)(smem + 17408);   // [64][41]

    int tid = threadIdx.x;
    int lane = tid & 63;
    int wm = tid >> 6;
    int lm = lane & 15;
    int quad = lane >> 4;
    int n0 = blockIdx.x * NNODE;
    short* H = Hs + wm * (16 * 72);

    // ================= edge phase =================
    {
        bf16x8 B1f[4], B2f[4][2];
        float b1c[4], b2c[4];
#pragma unroll
        for (int nt = 0; nt < 4; ++nt) {
            B1f[nt] = *(const bf16x8*)&W1bt[(nt * 16 + lm) * 32 + quad * 8];
            B2f[nt][0] = *(const bf16x8*)&W2bt[(nt * 16 + lm) * 64 + quad * 8];
            B2f[nt][1] = *(const bf16x8*)&W2bt[(nt * 16 + lm) * 64 + 32 + quad * 8];
            b1c[nt] = b1[nt * 16 + lm];
            b2c[nt] = b2[nt * 16 + lm];
        }

        for (int t = 0; t < 16; ++t) {
            int dst = n0 + wm * 16 + t;
            float mv = 0.f;
            if (dst < N) {
                unsigned int o0 = off[dst];
                int cnt = (int)(cur[dst] - o0);
                float pi0 = pos[dst * 3 + 0], pi1 = pos[dst * 3 + 1], pi2 = pos[dst * 3 + 2];
                float m0 = -INFINITY, m1 = -INFINITY, m2 = -INFINITY, m3 = -INFINITY;

                for (int base = 0; base < cnt; base += 16) {
                    bf16x8 A = {0, 0, 0, 0, 0, 0, 0, 0};
                    if (quad == 0) {
                        int i = min(base + lm, cnt - 1);   // pad = dup last (max idempotent)
                        int s = (int)list[o0 + i];
                        A[0] = (short)f2bf(x[s * 3 + 0]);
                        A[1] = (short)f2bf(x[s * 3 + 1]);
                        A[2] = (short)f2bf(x[s * 3 + 2]);
                        A[3] = (short)f2bf(pos[s * 3 + 0] - pi0);
                        A[4] = (short)f2bf(pos[s * 3 + 1] - pi1);
                        A[5] = (short)f2bf(pos[s * 3 + 2] - pi2);
                    }
                    // L1: h = relu(A @ W1 + b1)
#pragma unroll
                    for (int nt = 0; nt < 4; ++nt) {
                        f32x4 c = {0.f, 0.f, 0.f, 0.f};
                        c = mfma16(A, B1f[nt], c);
#pragma unroll
                        for (int r = 0; r < 4; ++r) {
                            float v = fmaxf(c[r] + b1c[nt], 0.f);
                            H[(quad * 4 + r) * 72 + nt * 16 + lm] = (short)f2bf(v);
                        }
                    }
                    bf16x8 A2a = *(const bf16x8*)&H[lm * 72 + quad * 8];
                    bf16x8 A2b = *(const bf16x8*)&H[lm * 72 + 32 + quad * 8];
                    // L2 + per-lane row max
                    {
                        f32x4 c = {0.f, 0.f, 0.f, 0.f};
                        c = mfma16(A2a, B2f[0][0], c); c = mfma16(A2b, B2f[0][1], c);
                        m0 = fmaxf(m0, fmaxf(fmaxf(c[0], c[1]), fmaxf(c[2], c[3])));
                    }
                    {
                        f32x4 c = {0.f, 0.f, 0.f, 0.f};
                        c = mfma16(A2a, B2f[1][0], c); c = mfma16(A2b, B2f[1][1], c);
                        m1 = fmaxf(m1, fmaxf(fmaxf(c[0], c[1]), fmaxf(c[2], c[3])));
                    }
                    {
                        f32x4 c = {0.f, 0.f, 0.f, 0.f};
                        c = mfma16(A2a, B2f[2][0], c); c = mfma16(A2b, B2f[2][1], c);
                        m2 = fmaxf(m2, fmaxf(fmaxf(c[0], c[1]), fmaxf(c[2], c[3])));
                    }
                    {
                        f32x4 c = {0.f, 0.f, 0.f, 0.f};
                        c = mfma16(A2a, B2f[3][0], c); c = mfma16(A2b, B2f[3][1], c);
                        m3 = fmaxf(m3, fmaxf(fmaxf(c[0], c[1]), fmaxf(c[2], c[3])));
                    }
                }
                m0 = fmaxf(m0, __shfl_xor(m0, 16, 64)); m0 = fmaxf(m0, __shfl_xor(m0, 32, 64));
                m1 = fmaxf(m1, __shfl_xor(m1, 16, 64)); m1 = fmaxf(m1, __shfl_xor(m1, 32, 64));
                m2 = fmaxf(m2, __shfl_xor(m2, 16, 64)); m2 = fmaxf(m2, __shfl_xor(m2, 32, 64));
                m3 = fmaxf(m3, __shfl_xor(m3, 16, 64)); m3 = fmaxf(m3, __shfl_xor(m3, 32, 64));
                mv = ((quad == 0) ? m0 : (quad == 1) ? m1 : (quad == 2) ? m2 : m3) + b2c[quad];
            }
            Ag[(wm * 16 + t) * 68 + lane] = mv;   // wave-private row
        }
    }

    // ================= node phase (no barrier: Ag rows wave-private) =================
    // ---- L3: g1 = relu(Ag @ W3 + b3), K=64 ----
    {
        bf16x8 A3[2];
#pragma unroll
        for (int f = 0; f < 2; ++f) {
            const float* p = Ag + (wm * 16 + lm) * 68 + f * 32 + quad * 8;
            float4 u = *(const float4*)p;
            float4 v = *(const float4*)(p + 4);
            bf16x8 t;
            t[0] = (short)f2bf(u.x); t[1] = (short)f2bf(u.y);
            t[2] = (short)f2bf(u.z); t[3] = (short)f2bf(u.w);
            t[4] = (short)f2bf(v.x); t[5] = (short)f2bf(v.y);
            t[6] = (short)f2bf(v.z); t[7] = (short)f2bf(v.w);
            A3[f] = t;
        }
#pragma unroll
        for (int nt = 0; nt < 8; ++nt) {
            const unsigned short* wb = (const unsigned short*)W3bt + (nt * 16 + lm) * 64 + quad * 8;
            f32x4 c = {0.f, 0.f, 0.f, 0.f};
            c = mfma16(A3[0], *(const bf16x8*)wb, c);
            c = mfma16(A3[1], *(const bf16x8*)(wb + 32), c);
            float bias = b3[nt * 16 + lm];
#pragma unroll
            for (int r = 0; r < 4; ++r) {
                float v = fmaxf(c[r] + bias, 0.f);
                G1s[(wm * 16 + quad * 4 + r) * 136 + nt * 16 + lm] = (short)f2bf(v);
            }
        }
    }

    bf16x8 A4[4];
#pragma unroll
    for (int f = 0; f < 4; ++f)
        A4[f] = *(const bf16x8*)&G1s[(wm * 16 + lm) * 136 + f * 32 + quad * 8];

    f32x4 acc3[4];
#pragma unroll
    for (int nt = 0; nt < 4; ++nt) {
        float b = b5[nt * 16 + lm];
        acc3[nt][0] = b; acc3[nt][1] = b; acc3[nt][2] = b; acc3[nt][3] = b;
    }

    // ---- L4+L5 fused over 16 chunks of 64 g2-channels ----
    for (int ch = 0; ch < 16; ++ch) {
#pragma unroll
        for (int nt = 0; nt < 4; ++nt) {
            const unsigned short* wb = W4bt + (size_t)(ch * 64 + nt * 16 + lm) * 128 + quad * 8;
            f32x4 c = {0.f, 0.f, 0.f, 0.f};
            c = mfma16(A4[0], *(const bf16x8*)wb, c);
            c = mfma16(A4[1], *(const bf16x8*)(wb + 32), c);
            c = mfma16(A4[2], *(const bf16x8*)(wb + 64), c);
            c = mfma16(A4[3], *(const bf16x8*)(wb + 96), c);
            float bias = b4[ch * 64 + nt * 16 + lm];
#pragma unroll
            for (int r = 0; r < 4; ++r) {
                float v = fmaxf(c[r] + bias, 0.f);
                G2s[(wm * 16 + quad * 4 + r) * 72 + nt * 16 + lm] = (short)f2bf(v);
            }
        }
        bf16x8 A5_0 = *(const bf16x8*)&G2s[(wm * 16 + lm) * 72 + quad * 8];
        bf16x8 A5_1 = *(const bf16x8*)&G2s[(wm * 16 + lm) * 72 + 32 + quad * 8];
#pragma unroll
        for (int nt = 0; nt < 4; ++nt) {
            const unsigned short* wb = W5bt + (size_t)(nt * 16 + lm) * 1024 + ch * 64 + quad * 8;
            acc3[nt] = mfma16(A5_0, *(const bf16x8*)wb, acc3[nt]);
            acc3[nt] = mfma16(A5_1, *(const bf16x8*)(wb + 32), acc3[nt]);
        }
    }

    // ---- stage relu(g3): G3f overlays Ag byte-exactly (wave-private rows) ----
#pragma unroll
    for (int nt = 0; nt < 4; ++nt)
#pragma unroll
        for (int r = 0; r < 4; ++r)
            G3f[(wm * 16 + quad * 4 + r) * 68 + nt * 16 + lm] = fmaxf(acc3[nt][r], 0.f);
    __syncthreads();

    // ---- fc: 64 nodes x 40 outputs (os overlays dead Hs/G1s-head) ----
    for (int idx = tid; idx < NNODE * 40; idx += 256) {
        int ln = idx / 40;
        int c = idx - ln * 40;
        float o = bf[c];
#pragma unroll 4
        for (int j = 0; j < 64; ++j)
            o = fmaf(G3f[ln * 68 + j], Wf[j * 40 + c], o);
        os[ln * 41 + c] = o;
    }
    __syncthreads();

    // ---- log_softmax + store ----
    if (tid < NNODE && n0 + tid < N) {
        int ln = tid;
        float mx = os[ln * 41 + 0];
#pragma unroll
        for (int c = 1; c < 40; ++c) mx = fmaxf(mx, os[ln * 41 + c]);
        float s = 0.f;
#pragma unroll
        for (int c = 0; c < 40; ++c) s += expf(os[ln * 41 + c] - mx);
        float ls = logf(s) + mx;
        float* op = out + (size_t)(n0 + ln) * 40;
#pragma unroll
        for (int c = 0; c < 40; ++c) op[c] = os[ln * 41 + c] - ls;
    }
}

// ============================ launch ============================
extern "C" void kernel_launch(void* const* d_in, const int* in_sizes, int n_in,
                              void* d_out, int out_size, void* d_ws, size_t ws_size,
                              hipStream_t stream) {
    const float* x   = (const float*)d_in[0];
    const float* pos = (const float*)d_in[1];
    const int*   ei  = (const int*)d_in[2];
    const float* W1  = (const float*)d_in[3];
    const float* b1  = (const float*)d_in[4];
    const float* W2  = (const float*)d_in[5];
    const float* b2  = (const float*)d_in[6];
    const float* W3  = (const float*)d_in[7];
    const float* b3  = (const float*)d_in[8];
    const float* W4  = (const float*)d_in[9];
    const float* b4  = (const float*)d_in[10];
    const float* W5  = (const float*)d_in[11];
    const float* b5  = (const float*)d_in[12];
    const float* Wf  = (const float*)d_in[13];
    const float* bf  = (const float*)d_in[14];
    float* out = (float*)d_out;

    int Nn = in_sizes[0] / 3;   // 50000
    int E  = in_sizes[2] / 2;   // 1600000

    char* w = (char*)d_ws;
    size_t p = 0;
    auto take = [&](size_t bytes) { size_t q = p; p = (p + bytes + 255) & ~size_t(255); return (void*)(w + q); };
    unsigned int*   off  = (unsigned int*)take((size_t)Nn * 4);
    unsigned int*   cnt  = (unsigned int*)take((size_t)Nn * 4);   // reused as cursor
    unsigned int*   list = (unsigned int*)take((size_t)(E + Nn) * 4);
    unsigned short* W1bt = (unsigned short*)take(2048 * 2);
    unsigned short* W2bt = (unsigned short*)take(4096 * 2);
    unsigned short* W3bt = (unsigned short*)take(8192 * 2);
    unsigned short* W4bt = (unsigned short*)take(131072 * 2);
    unsigned short* W5bt = (unsigned short*)take(65536 * 2);

    k_convert<<<(2048 + 4096 + 8192 + 131072 + 65536 + 255) / 256, 256, 0, stream>>>(
        W1, W2, W3, W4, W5, W1bt, W2bt, W3bt, W4bt, W5bt);

    k_init_cnt<<<(Nn + 255) / 256, 256, 0, stream>>>(cnt, Nn);
    k_count<<<(E + 255) / 256, 256, 0, stream>>>(ei, E, cnt);
    k_scan<<<1, 1024, 0, stream>>>(cnt, off, Nn);
    k_fill<<<(Nn + 255) / 256, 256, 0, stream>>>(off, cnt, list, Nn);
    k_scatter<<<(E + 255) / 256, 256, 0, stream>>>(ei, E, cnt, list);

    fused_kernel<<<(Nn + NNODE - 1) / NNODE, 256, 0, stream>>>(
        x, pos, off, cnt, list,
        W1bt, b1, W2bt, b2, W3bt, b3, W4bt, b4, W5bt, b5, Wf, bf, out, Nn);
}

// Round 11
// 679.230 us; speedup vs baseline: 1.0003x; 1.0003x over previous
//
#include <hip/hip_runtime.h>
#include <cstddef>
#include <cmath>

typedef __attribute__((ext_vector_type(8))) short bf16x8;
typedef __attribute__((ext_vector_type(4))) float f32x4;

static __device__ __forceinline__ f32x4 mfma16(bf16x8 a, bf16x8 b, f32x4 c) {
    return __builtin_amdgcn_mfma_f32_16x16x32_bf16(a, b, c, 0, 0, 0);
}
static __device__ __forceinline__ unsigned short f2bf(float f) {
    unsigned int u = __float_as_uint(f);
    return (unsigned short)((u + 0x7FFFu + ((u >> 16) & 1u)) >> 16);
}

// ============================ CSR build ============================
// cnt zeroed by hipMemsetAsync. Self-loop is NOT in the CSR list: the edge
// kernel injects it as implicit message 0 (max is idempotent, pad-safe).
__global__ void k_count(const int* __restrict__ ei, int E, unsigned int* __restrict__ cnt) {
    int idx = blockIdx.x * 256 + threadIdx.x;
    int e0 = idx * 4;
    if (e0 + 3 < E) {
        int4 d = ((const int4*)(ei + E))[idx];
        atomicAdd(&cnt[d.x], 1u);
        atomicAdd(&cnt[d.y], 1u);
        atomicAdd(&cnt[d.z], 1u);
        atomicAdd(&cnt[d.w], 1u);
    } else {
        for (int e = e0; e < E; ++e) atomicAdd(&cnt[ei[E + e]], 1u);
    }
}

// exclusive scan; writes off[] and resets cnt[] to cursor start (=off)
__global__ __launch_bounds__(1024) void k_scan(unsigned int* __restrict__ cnt,
                                               unsigned int* __restrict__ off, int N) {
    __shared__ unsigned int sums[1024];
    int t = threadIdx.x;
    int chunk = (N + 1023) >> 10;
    int lo = t * chunk, hi = min(lo + chunk, N);
    unsigned int s = 0;
    for (int i = lo; i < hi; ++i) s += cnt[i];
    sums[t] = s;
    __syncthreads();
    for (int d = 1; d < 1024; d <<= 1) {
        unsigned int v = (t >= d) ? sums[t - d] : 0u;
        __syncthreads();
        sums[t] += v;
        __syncthreads();
    }
    unsigned int run = (t == 0) ? 0u : sums[t - 1];
    for (int i = lo; i < hi; ++i) {
        unsigned int c = cnt[i];
        off[i] = run;
        cnt[i] = run;       // cursor start
        run += c;
    }
}

__global__ void k_scatter(const int* __restrict__ ei, int E,
                          unsigned int* __restrict__ cur, unsigned int* __restrict__ list) {
    int idx = blockIdx.x * 256 + threadIdx.x;
    int e0 = idx * 4;
    if (e0 + 3 < E) {
        int4 s = ((const int4*)ei)[idx];
        int4 d = ((const int4*)(ei + E))[idx];
        unsigned int p0 = atomicAdd(&cur[d.x], 1u);
        unsigned int p1 = atomicAdd(&cur[d.y], 1u);
        unsigned int p2 = atomicAdd(&cur[d.z], 1u);
        unsigned int p3 = atomicAdd(&cur[d.w], 1u);
        list[p0] = (unsigned int)s.x;
        list[p1] = (unsigned int)s.y;
        list[p2] = (unsigned int)s.z;
        list[p3] = (unsigned int)s.w;
    } else {
        for (int e = e0; e < E; ++e) {
            int d = ei[E + e];
            unsigned int p = atomicAdd(&cur[d], 1u);
            list[p] = (unsigned int)ei[e];
        }
    }
}

// ====== weight converter: f32 [K][N] -> bf16 transposed [N][K] (W1 K-padded to 32) ======
__global__ void k_convert(const float* __restrict__ W1, const float* __restrict__ W2,
                          const float* __restrict__ W3, const float* __restrict__ W4,
                          const float* __restrict__ W5,
                          unsigned short* __restrict__ W1bt, unsigned short* __restrict__ W2bt,
                          unsigned short* __restrict__ W3bt, unsigned short* __restrict__ W4bt,
                          unsigned short* __restrict__ W5bt) {
    int id = blockIdx.x * 256 + threadIdx.x;
    if (id < 2048) {                               // W1: [6][64] -> [64][32] zero-padded
        int n = id >> 5, k = id & 31;
        W1bt[id] = (k < 6) ? f2bf(W1[k * 64 + n]) : (unsigned short)0;
    } else if (id < 2048 + 4096) {                 // W2: [64][64] -> [64][64]
        int t = id - 2048;
        int n = t >> 6, k = t & 63;
        W2bt[t] = f2bf(W2[k * 64 + n]);
    } else if (id < 6144 + 8192) {                 // W3: [64][128] -> [128][64]
        int t = id - 6144;
        int n = t >> 6, k = t & 63;
        W3bt[t] = f2bf(W3[k * 128 + n]);
    } else if (id < 14336 + 131072) {              // W4: [128][1024] -> [1024][128]
        int t = id - 14336;
        int n = t >> 7, k = t & 127;
        W4bt[t] = f2bf(W4[k * 1024 + n]);
    } else if (id < 145408 + 65536) {              // W5: [1024][64] -> [64][1024]
        int t = id - 145408;
        int n = t >> 10, k = t & 1023;
        W5bt[t] = f2bf(W5[k * 64 + n]);
    }
}

// ===================== edge kernel: MFMA, one wave per dst, 16 msgs/tile =====================
// Message 0 = implicit self-loop (src=dst, pos diff 0); messages 1..ecnt from CSR list.
// Tile padding duplicates the last message (max idempotent). h C->A round-trip via
// wave-private LDS patch (no barriers).
#define TPB_E 256
#define EDGE_WPB 4
__global__ __launch_bounds__(TPB_E, 3) void edge_kernel(
    const float* __restrict__ x, const float* __restrict__ pos,
    const unsigned int* __restrict__ off, const unsigned int* __restrict__ cur,
    const unsigned int* __restrict__ list,
    const unsigned short* __restrict__ W1bt, const float* __restrict__ b1,
    const unsigned short* __restrict__ W2bt, const float* __restrict__ b2,
    float* __restrict__ agg, int N, int dstStride)
{
    __shared__ __align__(16) short Hs[4][16 * 72];

    int tid = threadIdx.x;
    int lane = tid & 63;
    int w = tid >> 6;
    int lm = lane & 15;
    int quad = lane >> 4;
    short* H = Hs[w];
    int dst0 = blockIdx.x * EDGE_WPB + w;

    bf16x8 B1f[4], B2f[4][2];
    float b1c[4], b2c[4];
#pragma unroll
    for (int nt = 0; nt < 4; ++nt) {
        B1f[nt] = *(const bf16x8*)&W1bt[(nt * 16 + lm) * 32 + quad * 8];
        B2f[nt][0] = *(const bf16x8*)&W2bt[(nt * 16 + lm) * 64 + quad * 8];
        B2f[nt][1] = *(const bf16x8*)&W2bt[(nt * 16 + lm) * 64 + 32 + quad * 8];
        b1c[nt] = b1[nt * 16 + lm];
        b2c[nt] = b2[nt * 16 + lm];
    }

    for (int dst = dst0; dst < N; dst += dstStride) {
        unsigned int o0 = off[dst];
        int ecnt = (int)(cur[dst] - o0);
        int M = ecnt + 1;                    // + implicit self message
        float pi0 = pos[dst * 3 + 0], pi1 = pos[dst * 3 + 1], pi2 = pos[dst * 3 + 2];

        float m0 = -INFINITY, m1 = -INFINITY, m2 = -INFINITY, m3 = -INFINITY;

        for (int base = 0; base < M; base += 16) {
            bf16x8 A = {0, 0, 0, 0, 0, 0, 0, 0};
            if (quad == 0) {
                int i = min(base + lm, M - 1);        // pad = dup last
                int s = (i == 0) ? dst : (int)list[o0 + i - 1];
                A[0] = (short)f2bf(x[s * 3 + 0]);
                A[1] = (short)f2bf(x[s * 3 + 1]);
                A[2] = (short)f2bf(x[s * 3 + 2]);
                A[3] = (short)f2bf(pos[s * 3 + 0] - pi0);
                A[4] = (short)f2bf(pos[s * 3 + 1] - pi1);
                A[5] = (short)f2bf(pos[s * 3 + 2] - pi2);
            }
            // L1: h = relu(A @ W1 + b1)
#pragma unroll
            for (int nt = 0; nt < 4; ++nt) {
                f32x4 c = {0.f, 0.f, 0.f, 0.f};
                c = mfma16(A, B1f[nt], c);
#pragma unroll
                for (int r = 0; r < 4; ++r) {
                    float v = fmaxf(c[r] + b1c[nt], 0.f);
                    H[(quad * 4 + r) * 72 + nt * 16 + lm] = (short)f2bf(v);
                }
            }
            bf16x8 A2a = *(const bf16x8*)&H[lm * 72 + quad * 8];
            bf16x8 A2b = *(const bf16x8*)&H[lm * 72 + 32 + quad * 8];
            // L2 + per-lane row max
            {
                f32x4 c = {0.f, 0.f, 0.f, 0.f};
                c = mfma16(A2a, B2f[0][0], c); c = mfma16(A2b, B2f[0][1], c);
                m0 = fmaxf(m0, fmaxf(fmaxf(c[0], c[1]), fmaxf(c[2], c[3])));
            }
            {
                f32x4 c = {0.f, 0.f, 0.f, 0.f};
                c = mfma16(A2a, B2f[1][0], c); c = mfma16(A2b, B2f[1][1], c);
                m1 = fmaxf(m1, fmaxf(fmaxf(c[0], c[1]), fmaxf(c[2], c[3])));
            }
            {
                f32x4 c = {0.f, 0.f, 0.f, 0.f};
                c = mfma16(A2a, B2f[2][0], c); c = mfma16(A2b, B2f[2][1], c);
                m2 = fmaxf(m2, fmaxf(fmaxf(c[0], c[1]), fmaxf(c[2], c[3])));
            }
            {
                f32x4 c = {0.f, 0.f, 0.f, 0.f};
                c = mfma16(A2a, B2f[3][0], c); c = mfma16(A2b, B2f[3][1], c);
                m3 = fmaxf(m3, fmaxf(fmaxf(c[0], c[1]), fmaxf(c[2], c[3])));
            }
        }

        m0 = fmaxf(m0, __shfl_xor(m0, 16, 64)); m0 = fmaxf(m0, __shfl_xor(m0, 32, 64));
        m1 = fmaxf(m1, __shfl_xor(m1, 16, 64)); m1 = fmaxf(m1, __shfl_xor(m1, 32, 64));
        m2 = fmaxf(m2, __shfl_xor(m2, 16, 64)); m2 = fmaxf(m2, __shfl_xor(m2, 32, 64));
        m3 = fmaxf(m3, __shfl_xor(m3, 16, 64)); m3 = fmaxf(m3, __shfl_xor(m3, 32, 64));

        float mv = (quad == 0) ? m0 : (quad == 1) ? m1 : (quad == 2) ? m2 : m3;
        agg[(size_t)dst * 64 + lane] = mv + b2c[quad];
    }
}

// ===================== node kernel: bf16 MFMA GEMM chain, 64 nodes/block =====================
// R10 lesson: chunk loop was latency-serialized on L2 weight loads. Fix: batch all
// 24 chunk weight loads (16x W4 b128 + 8x W5 b128) into registers BEFORE any MFMA
// -> one latency exposure per chunk. ~145 live VGPRs, all unrolled straight-line.
#define NNODE 64
__global__ __launch_bounds__(256, 2) void node_kernel(
    const float* __restrict__ agg,
    const unsigned short* __restrict__ W3bt, const float* __restrict__ b3,
    const unsigned short* __restrict__ W4bt, const float* __restrict__ b4,
    const unsigned short* __restrict__ W5bt, const float* __restrict__ b5,
    const float* __restrict__ Wf, const float* __restrict__ bf,
    float* __restrict__ out, int N)
{
    __shared__ __align__(16) char smem[17408 + 10496];
    short* G1s = (short*)smem;
    float* G3f = (float*)smem;
    short* G2s = (short*)(smem + 17408);
    float* os  = (float*)(smem + 17408);

    int tid = threadIdx.x;
    int lane = tid & 63;
    int wm = tid >> 6;
    int lm = lane & 15;
    int quad = lane >> 4;
    int n0 = blockIdx.x * NNODE;

    // ---- L3: g1[64x128] = relu(agg @ W3 + b3), K=64 ----
    {
        int arow = min(n0 + wm * 16 + lm, N - 1);
        bf16x8 A3[2];
#pragma unroll
        for (int f = 0; f < 2; ++f) {
            const float* p = agg + (size_t)arow * 64 + f * 32 + quad * 8;
            float4 u = *(const float4*)p;
            float4 v = *(const float4*)(p + 4);
            bf16x8 t;
            t[0] = (short)f2bf(u.x); t[1] = (short)f2bf(u.y);
            t[2] = (short)f2bf(u.z); t[3] = (short)f2bf(u.w);
            t[4] = (short)f2bf(v.x); t[5] = (short)f2bf(v.y);
            t[6] = (short)f2bf(v.z); t[7] = (short)f2bf(v.w);
            A3[f] = t;
        }
#pragma unroll
        for (int nt = 0; nt < 8; ++nt) {
            const unsigned short* wb = W3bt + (nt * 16 + lm) * 64 + quad * 8;
            f32x4 c = {0.f, 0.f, 0.f, 0.f};
            c = mfma16(A3[0], *(const bf16x8*)wb, c);
            c = mfma16(A3[1], *(const bf16x8*)(wb + 32), c);
            float bias = b3[nt * 16 + lm];
#pragma unroll
            for (int r = 0; r < 4; ++r) {
                float v = fmaxf(c[r] + bias, 0.f);
                G1s[(wm * 16 + quad * 4 + r) * 136 + nt * 16 + lm] = (short)f2bf(v);
            }
        }
    }

    bf16x8 A4[4];
#pragma unroll
    for (int f = 0; f < 4; ++f)
        A4[f] = *(const bf16x8*)&G1s[(wm * 16 + lm) * 136 + f * 32 + quad * 8];

    f32x4 acc3[4];
#pragma unroll
    for (int nt = 0; nt < 4; ++nt) {
        float b = b5[nt * 16 + lm];
        acc3[nt][0] = b; acc3[nt][1] = b; acc3[nt][2] = b; acc3[nt][3] = b;
    }

    for (int ch = 0; ch < 16; ++ch) {
        // batch-issue ALL chunk weight loads first (independent of LDS/compute)
        bf16x8 w4r[4][4], w5r[4][2];
#pragma unroll
        for (int nt = 0; nt < 4; ++nt) {
            const unsigned short* wb = W4bt + (size_t)(ch * 64 + nt * 16 + lm) * 128 + quad * 8;
            w4r[nt][0] = *(const bf16x8*)wb;
            w4r[nt][1] = *(const bf16x8*)(wb + 32);
            w4r[nt][2] = *(const bf16x8*)(wb + 64);
            w4r[nt][3] = *(const bf16x8*)(wb + 96);
        }
#pragma unroll
        for (int nt = 0; nt < 4; ++nt) {
            const unsigned short* wb = W5bt + (size_t)(nt * 16 + lm) * 1024 + ch * 64 + quad * 8;
            w5r[nt][0] = *(const bf16x8*)wb;
            w5r[nt][1] = *(const bf16x8*)(wb + 32);
        }
        // L4: g2 chunk = relu(g1 @ W4chunk + b4)
#pragma unroll
        for (int nt = 0; nt < 4; ++nt) {
            f32x4 c = {0.f, 0.f, 0.f, 0.f};
            c = mfma16(A4[0], w4r[nt][0], c);
            c = mfma16(A4[1], w4r[nt][1], c);
            c = mfma16(A4[2], w4r[nt][2], c);
            c = mfma16(A4[3], w4r[nt][3], c);
            float bias = b4[ch * 64 + nt * 16 + lm];
#pragma unroll
            for (int r = 0; r < 4; ++r) {
                float v = fmaxf(c[r] + bias, 0.f);
                G2s[(wm * 16 + quad * 4 + r) * 72 + nt * 16 + lm] = (short)f2bf(v);
            }
        }
        // L5: g3 += g2chunk @ W5chunk (C->A via wave-private LDS)
        bf16x8 A5_0 = *(const bf16x8*)&G2s[(wm * 16 + lm) * 72 + quad * 8];
        bf16x8 A5_1 = *(const bf16x8*)&G2s[(wm * 16 + lm) * 72 + 32 + quad * 8];
#pragma unroll
        for (int nt = 0; nt < 4; ++nt) {
            acc3[nt] = mfma16(A5_0, w5r[nt][0], acc3[nt]);
            acc3[nt] = mfma16(A5_1, w5r[nt][1], acc3[nt]);
        }
    }

#pragma unroll
    for (int nt = 0; nt < 4; ++nt)
#pragma unroll
        for (int r = 0; r < 4; ++r)
            G3f[(wm * 16 + quad * 4 + r) * 68 + nt * 16 + lm] = fmaxf(acc3[nt][r], 0.f);
    __syncthreads();

    for (int idx = tid; idx < NNODE * 40; idx += 256) {
        int ln = idx / 40;
        int c = idx - ln * 40;
        float o = bf[c];
#pragma unroll 4
        for (int j = 0; j < 64; ++j)
            o = fmaf(G3f[ln * 68 + j], Wf[j * 40 + c], o);
        os[ln * 41 + c] = o;
    }
    __syncthreads();

    if (tid < NNODE && n0 + tid < N) {
        int ln = tid;
        float mx = os[ln * 41 + 0];
#pragma unroll
        for (int c = 1; c < 40; ++c) mx = fmaxf(mx, os[ln * 41 + c]);
        float s = 0.f;
#pragma unroll
        for (int c = 0; c < 40; ++c) s += expf(os[ln * 41 + c] - mx);
        float ls = logf(s) + mx;
        float* op = out + (size_t)(n0 + tid) * 40;
#pragma unroll
        for (int c = 0; c < 40; ++c) op[c] = os[ln * 41 + c] - ls;
    }
}

// ============================ launch ============================
extern "C" void kernel_launch(void* const* d_in, const int* in_sizes, int n_in,
                              void* d_out, int out_size, void* d_ws, size_t ws_size,
                              hipStream_t stream) {
    const float* x   = (const float*)d_in[0];
    const float* pos = (const float*)d_in[1];
    const int*   ei  = (const int*)d_in[2];
    const float* W1  = (const float*)d_in[3];
    const float* b1  = (const float*)d_in[4];
    const float* W2  = (const float*)d_in[5];
    const float* b2  = (const float*)d_in[6];
    const float* W3  = (const float*)d_in[7];
    const float* b3  = (const float*)d_in[8];
    const float* W4  = (const float*)d_in[9];
    const float* b4  = (const float*)d_in[10];
    const float* W5  = (const float*)d_in[11];
    const float* b5  = (const float*)d_in[12];
    const float* Wf  = (const float*)d_in[13];
    const float* bf  = (const float*)d_in[14];
    float* out = (float*)d_out;

    int Nn = in_sizes[0] / 3;   // 50000
    int E  = in_sizes[2] / 2;   // 1600000

    char* w = (char*)d_ws;
    size_t p = 0;
    auto take = [&](size_t bytes) { size_t q = p; p = (p + bytes + 255) & ~size_t(255); return (void*)(w + q); };
    unsigned int*   off  = (unsigned int*)take((size_t)Nn * 4);
    unsigned int*   cnt  = (unsigned int*)take((size_t)Nn * 4);   // count -> cursor
    unsigned int*   list = (unsigned int*)take((size_t)E * 4);
    float*          agg  = (float*)take((size_t)Nn * 64 * 4);
    unsigned short* W1bt = (unsigned short*)take(2048 * 2);
    unsigned short* W2bt = (unsigned short*)take(4096 * 2);
    unsigned short* W3bt = (unsigned short*)take(8192 * 2);
    unsigned short* W4bt = (unsigned short*)take(131072 * 2);
    unsigned short* W5bt = (unsigned short*)take(65536 * 2);

    k_convert<<<(2048 + 4096 + 8192 + 131072 + 65536 + 255) / 256, 256, 0, stream>>>(
        W1, W2, W3, W4, W5, W1bt, W2bt, W3bt, W4bt, W5bt);

    hipMemsetAsync(cnt, 0, (size_t)Nn * 4, stream);
    int q4 = (E + 3) / 4;
    k_count<<<(q4 + 255) / 256, 256, 0, stream>>>(ei, E, cnt);
    k_scan<<<1, 1024, 0, stream>>>(cnt, off, Nn);
    k_scatter<<<(q4 + 255) / 256, 256, 0, stream>>>(ei, E, cnt, list);

    int totalWaves = (Nn + 3) / 4;
    int eBlocks = (totalWaves + EDGE_WPB - 1) / EDGE_WPB;
    int dstStride = eBlocks * EDGE_WPB;
    edge_kernel<<<eBlocks, TPB_E, 0, stream>>>(
        x, pos, off, cnt, list, W1bt, b1, W2bt, b2, agg, Nn, dstStride);

    node_kernel<<<(Nn + NNODE - 1) / NNODE, 256, 0, stream>>>(
        agg, W3bt, b3, W4bt, b4, W5bt, b5, Wf, bf, out, Nn);
}